// Round 2
// baseline (47.715 us; speedup 1.0000x reference)
//
#include <hip/hip_runtime.h>
#include <math.h>

#define NQ 4
#define DIN 256
#define DOUT 64
#define NLAYER 2
#define TPB 256
#define K1_ROWS 64          // rows per K1 block (4 chunks of 16)

__device__ __forceinline__ float tanh_fast(float y) {
    float e = __expf(2.0f * y);
    return 1.0f - 2.0f / (e + 1.0f);
}

// ---------------- K1: f = pi * tanh(x @ W1^T + b1)  (pure 128 MB stream) ----
__global__ __launch_bounds__(TPB) void qp_k1(
    const float* __restrict__ x, const float* __restrict__ W1,
    const float* __restrict__ b1, float* __restrict__ fbuf, int fstride)
{
    __shared__ __align__(16) float w1s[NQ][DIN];   // 4 KB
    const int t = threadIdx.x;
    ((float4*)&w1s[0][0])[t] = ((const float4*)W1)[t];   // 256 float4 = 4x256 floats
    const float4 bv = *(const float4*)b1;                // broadcast load
    __syncthreads();

    const int wave = t >> 6, lane = t & 63;
    const int rsub = lane >> 4;      // row within 4-row group
    const int cc   = lane & 15;      // float4 chunk
    const int rowbase = blockIdx.x * K1_ROWS + wave * 4 + rsub;

    #pragma unroll
    for (int it = 0; it < K1_ROWS / 16; ++it) {
        const int row = rowbase + it * 16;
        const float4* xr = (const float4*)(x + (size_t)row * DIN);
        float a0 = 0.f, a1 = 0.f, a2 = 0.f, a3 = 0.f;
        #pragma unroll
        for (int p = 0; p < 4; ++p) {
            const float4 xv  = xr[p*16 + cc];
            const float4 w0v = ((const float4*)&w1s[0][0])[p*16 + cc];
            const float4 w1v = ((const float4*)&w1s[1][0])[p*16 + cc];
            const float4 w2v = ((const float4*)&w1s[2][0])[p*16 + cc];
            const float4 w3v = ((const float4*)&w1s[3][0])[p*16 + cc];
            a0 = fmaf(xv.x,w0v.x, fmaf(xv.y,w0v.y, fmaf(xv.z,w0v.z, fmaf(xv.w,w0v.w, a0))));
            a1 = fmaf(xv.x,w1v.x, fmaf(xv.y,w1v.y, fmaf(xv.z,w1v.z, fmaf(xv.w,w1v.w, a1))));
            a2 = fmaf(xv.x,w2v.x, fmaf(xv.y,w2v.y, fmaf(xv.z,w2v.z, fmaf(xv.w,w2v.w, a2))));
            a3 = fmaf(xv.x,w3v.x, fmaf(xv.y,w3v.y, fmaf(xv.z,w3v.z, fmaf(xv.w,w3v.w, a3))));
        }
        #pragma unroll
        for (int d = 1; d < 16; d <<= 1) {
            a0 += __shfl_xor(a0, d, 64);
            a1 += __shfl_xor(a1, d, 64);
            a2 += __shfl_xor(a2, d, 64);
            a3 += __shfl_xor(a3, d, 64);
        }
        if (cc == 0) {
            const float PI = 3.14159265358979f;
            float4 o;
            o.x = PI * tanh_fast(a0 + bv.x);
            o.y = PI * tanh_fast(a1 + bv.y);
            o.z = PI * tanh_fast(a2 + bv.z);
            o.w = PI * tanh_fast(a3 + bv.w);
            *(float4*)(fbuf + (size_t)row * fstride) = o;
        }
    }
}

// ---------------- K2: 4-qubit circuit + out = q @ W2^T + b2 -----------------
__global__ __launch_bounds__(TPB) void qp_k2(
    const float* __restrict__ fbuf, int fstride,
    const float* __restrict__ wts, const float* __restrict__ W2,
    const float* __restrict__ b2, float* __restrict__ out)
{
    __shared__ __align__(16) float qs[TPB][NQ];    // 4 KB
    __shared__ __align__(16) float w2s[DOUT][NQ];  // 1 KB
    __shared__ __align__(16) float us[8][8];       // Rot gate matrices
    __shared__ float b2s[DOUT];

    const int t = threadIdx.x;
    const int brow = blockIdx.x * TPB;

    if (t < 64) {
        ((float4*)&w2s[0][0])[t] = ((const float4*)W2)[t];
        b2s[t] = b2[t];
    }
    if (t < 8) {
        const float phi = wts[t*3 + 0], th = wts[t*3 + 1], om = wts[t*3 + 2];
        float sth, cth; sincosf(0.5f*th, &sth, &cth);
        float sp, cp;   sincosf(0.5f*(phi+om), &sp, &cp);
        float sm, cm;   sincosf(0.5f*(phi-om), &sm, &cm);
        us[t][0] =  cth*cp; us[t][1] = -cth*sp;
        us[t][2] = -sth*cm; us[t][3] = -sth*sm;
        us[t][4] =  sth*cm; us[t][5] = -sth*sm;
        us[t][6] =  cth*cp; us[t][7] =  cth*sp;
    }
    const float4 fv = *(const float4*)(fbuf + (size_t)(brow + t) * fstride);
    __syncthreads();

    {
        const float fq[4] = {fv.x, fv.y, fv.z, fv.w};
        const float IS2 = 0.70710678118654752f;
        float vr[4][2], vi[4][2];
        #pragma unroll
        for (int i = 0; i < 4; ++i) {
            const float fi = fq[i];
            const float f2 = fi*fi;
            const float ca = rsqrtf(1.0f + f2);
            const float ch = sqrtf(0.5f*(1.0f + ca));
            const float sh = copysignf(sqrtf(fmaxf(0.5f*(1.0f - ca), 0.0f)), fi);
            const float cb = rsqrtf(1.0f + f2*f2);
            const float cbh = sqrtf(0.5f*(1.0f + cb));
            const float sbh = sqrtf(fmaxf(0.5f*(1.0f - cb), 0.0f));
            const float u0 = (ch - sh) * IS2;
            const float u1 = (ch + sh) * IS2;
            vr[i][0] = u0 * cbh;  vi[i][0] = -u0 * sbh;
            vr[i][1] = u1 * cbh;  vi[i][1] =  u1 * sbh;
        }
        float ar[16], ai[16];
        #pragma unroll
        for (int i0 = 0; i0 < 2; ++i0)
        #pragma unroll
        for (int i1 = 0; i1 < 2; ++i1) {
            const float pr  = vr[0][i0]*vr[1][i1] - vi[0][i0]*vi[1][i1];
            const float pim = vr[0][i0]*vi[1][i1] + vi[0][i0]*vr[1][i1];
            #pragma unroll
            for (int i2 = 0; i2 < 2; ++i2)
            #pragma unroll
            for (int i3 = 0; i3 < 2; ++i3) {
                const float qr  = vr[2][i2]*vr[3][i3] - vi[2][i2]*vi[3][i3];
                const float qim = vr[2][i2]*vi[3][i3] + vi[2][i2]*vr[3][i3];
                const int idx = i0*8 + i1*4 + i2*2 + i3;
                ar[idx] = pr*qr - pim*qim;
                ai[idx] = pr*qim + pim*qr;
            }
        }
        #pragma unroll
        for (int l = 0; l < NLAYER; ++l) {
            constexpr int cpairs[8][2] = {{0,1},{1,2},{2,3},{3,0},{0,2},{1,3},{2,0},{3,1}};
            #pragma unroll
            for (int g = 0; g < 8; ++g) {
                const int bc = 8 >> cpairs[g][0];
                const int bt = 8 >> cpairs[g][1];
                #pragma unroll
                for (int m = 0; m < 16; ++m) {
                    if ((m & bc) && !(m & bt)) {
                        const int m2 = m | bt;
                        float tr = ar[m]; ar[m] = ar[m2]; ar[m2] = tr;
                        float ti = ai[m]; ai[m] = ai[m2]; ai[m2] = ti;
                    }
                }
            }
            #pragma unroll
            for (int i = 0; i < 4; ++i) {
                const float* u = &us[l*4 + i][0];
                const float u00r=u[0], u00i=u[1], u01r=u[2], u01i=u[3];
                const float u10r=u[4], u10i=u[5], u11r=u[6], u11i=u[7];
                const int bq = 8 >> i;
                #pragma unroll
                for (int m = 0; m < 16; ++m) {
                    if (!(m & bq)) {
                        const int m2 = m | bq;
                        const float a0r=ar[m], a0i=ai[m], a1r=ar[m2], a1i=ai[m2];
                        ar[m]  = u00r*a0r - u00i*a0i + u01r*a1r - u01i*a1i;
                        ai[m]  = u00r*a0i + u00i*a0r + u01r*a1i + u01i*a1r;
                        ar[m2] = u10r*a0r - u10i*a0i + u11r*a1r - u11i*a1i;
                        ai[m2] = u10r*a0i + u10i*a0r + u11r*a1i + u11i*a1r;
                    }
                }
            }
        }
        float z0=0.f, z1=0.f, z2=0.f, z3=0.f;
        #pragma unroll
        for (int m = 0; m < 16; ++m) {
            const float p = ar[m]*ar[m] + ai[m]*ai[m];
            z0 += (m & 8) ? -p : p;
            z1 += (m & 4) ? -p : p;
            z2 += (m & 2) ? -p : p;
            z3 += (m & 1) ? -p : p;
        }
        float4 qv; qv.x=z0; qv.y=z1; qv.z=z2; qv.w=z3;
        ((float4*)qs)[t] = qv;
    }

    // phase 3: out = q @ W2^T + b2, coalesced float4 stores
    const int j4 = t & 15;
    float w2r[4][4], b2r[4];
    #pragma unroll
    for (int jj = 0; jj < 4; ++jj) {
        const int j = j4*4 + jj;
        #pragma unroll
        for (int i = 0; i < 4; ++i) w2r[jj][i] = w2s[j][i];
        b2r[jj] = b2s[j];
    }
    __syncthreads();
    const int rb = t >> 4;
    #pragma unroll 4
    for (int e = 0; e < 16; ++e) {
        const int r = e*16 + rb;
        const float4 q = ((const float4*)qs)[r];
        float4 o;
        o.x = fmaf(q.x,w2r[0][0], fmaf(q.y,w2r[0][1], fmaf(q.z,w2r[0][2], fmaf(q.w,w2r[0][3], b2r[0]))));
        o.y = fmaf(q.x,w2r[1][0], fmaf(q.y,w2r[1][1], fmaf(q.z,w2r[1][2], fmaf(q.w,w2r[1][3], b2r[1]))));
        o.z = fmaf(q.x,w2r[2][0], fmaf(q.y,w2r[2][1], fmaf(q.z,w2r[2][2], fmaf(q.w,w2r[2][3], b2r[2]))));
        o.w = fmaf(q.x,w2r[3][0], fmaf(q.y,w2r[3][1], fmaf(q.z,w2r[3][2], fmaf(q.w,w2r[3][3], b2r[3]))));
        ((float4*)(out + (size_t)(brow + r) * DOUT))[j4] = o;
    }
}

extern "C" void kernel_launch(void* const* d_in, const int* in_sizes, int n_in,
                              void* d_out, int out_size, void* d_ws, size_t ws_size,
                              hipStream_t stream) {
    const float* x  = (const float*)d_in[0];
    const float* W1 = (const float*)d_in[1];
    const float* b1 = (const float*)d_in[2];
    const float* wt = (const float*)d_in[3];
    const float* W2 = (const float*)d_in[4];
    const float* b2 = (const float*)d_in[5];
    float* out = (float*)d_out;
    const int B = in_sizes[0] / DIN;        // 131072

    // f buffer: contiguous in workspace if it fits, else embedded in out rows
    float* fbuf;
    int fstride;
    if (ws_size >= (size_t)B * 4 * sizeof(float)) {
        fbuf = (float*)d_ws; fstride = 4;
    } else {
        fbuf = out; fstride = DOUT;   // K2 reads its row's f before overwriting
    }

    qp_k1<<<B / K1_ROWS, TPB, 0, stream>>>(x, W1, b1, fbuf, fstride);
    qp_k2<<<B / TPB, TPB, 0, stream>>>(fbuf, fstride, wt, W2, b2, out);
}

// Round 3
// 43.558 us; speedup vs baseline: 1.0954x; 1.0954x over previous
//
#include <hip/hip_runtime.h>
#include <math.h>

#define NQ 4
#define DIN 256
#define DOUT 64
#define NLAYER 2
#define TPB 256
#define BROWS 64            // rows per block

__device__ __forceinline__ float tanh_fast(float y) {
    float e = __expf(2.0f * y);
    return 1.0f - 2.0f / (e + 1.0f);
}

__global__ __launch_bounds__(TPB, 4) void qp_fused(
    const float* __restrict__ x,  const float* __restrict__ W1,
    const float* __restrict__ b1, const float* __restrict__ wts,
    const float* __restrict__ W2, const float* __restrict__ b2,
    float* __restrict__ out)
{
    __shared__ __align__(16) float fs[BROWS][NQ];   // 1 KB
    __shared__ __align__(16) float qs[BROWS][NQ];   // 1 KB
    __shared__ __align__(16) float w2s[DOUT][NQ];   // 1 KB
    __shared__ __align__(16) float us[8][8];        // Rot gates
    __shared__ float b2s[DOUT];

    const int t = threadIdx.x;
    const int wave = t >> 6, lane = t & 63;
    const int rsub = lane >> 4;          // row within 4-row group
    const int cc   = lane & 15;          // float4 chunk (16 per row-quarter)
    const int brow = blockIdx.x * BROWS;

    // ---- phase 0: small staging (no sync needed before phase 1)
    if (t < 64) {
        ((float4*)&w2s[0][0])[t] = ((const float4*)W2)[t];
        b2s[t] = b2[t];
    }
    if (t < 8) {
        const float phi = wts[t*3 + 0], th = wts[t*3 + 1], om = wts[t*3 + 2];
        float sth, cth; sincosf(0.5f*th, &sth, &cth);
        float sp, cp;   sincosf(0.5f*(phi+om), &sp, &cp);
        float sm, cm;   sincosf(0.5f*(phi-om), &sm, &cm);
        us[t][0] =  cth*cp; us[t][1] = -cth*sp;
        us[t][2] = -sth*cm; us[t][3] = -sth*sm;
        us[t][4] =  sth*cm; us[t][5] = -sth*sm;
        us[t][6] =  cth*cp; us[t][7] =  cth*sp;
    }

    // ---- phase 1: f = pi*tanh(x@W1^T+b1), weights in REGISTERS (no LDS in loop)
    {
        // lane's W1 fragment: w[q][p] = W1 float4 at [q][p*16+cc]
        float4 w[4][4];
        #pragma unroll
        for (int q = 0; q < 4; ++q)
            #pragma unroll
            for (int p = 0; p < 4; ++p)
                w[q][p] = ((const float4*)W1)[q*64 + p*16 + cc];
        const float4 bv = *(const float4*)b1;

        const int rowbase = brow + wave*4 + rsub;   // + it*16
        const float4* xr0 = (const float4*)(x + (size_t)rowbase * DIN);

        float4 xv0 = xr0[cc], xv1 = xr0[16+cc], xv2 = xr0[32+cc], xv3 = xr0[48+cc];
        #pragma unroll
        for (int it = 0; it < BROWS/16; ++it) {
            float4 nv0, nv1, nv2, nv3;
            if (it < BROWS/16 - 1) {        // prefetch next 16-row group
                const float4* xr = (const float4*)(x + (size_t)(rowbase + (it+1)*16) * DIN);
                nv0 = xr[cc]; nv1 = xr[16+cc]; nv2 = xr[32+cc]; nv3 = xr[48+cc];
            }
            float a0=0.f, a1=0.f, a2=0.f, a3=0.f;
            #pragma unroll
            for (int p = 0; p < 4; ++p) {
                const float4 xv = (p==0)?xv0:(p==1)?xv1:(p==2)?xv2:xv3;
                a0 = fmaf(xv.x,w[0][p].x, fmaf(xv.y,w[0][p].y, fmaf(xv.z,w[0][p].z, fmaf(xv.w,w[0][p].w, a0))));
                a1 = fmaf(xv.x,w[1][p].x, fmaf(xv.y,w[1][p].y, fmaf(xv.z,w[1][p].z, fmaf(xv.w,w[1][p].w, a1))));
                a2 = fmaf(xv.x,w[2][p].x, fmaf(xv.y,w[2][p].y, fmaf(xv.z,w[2][p].z, fmaf(xv.w,w[2][p].w, a2))));
                a3 = fmaf(xv.x,w[3][p].x, fmaf(xv.y,w[3][p].y, fmaf(xv.z,w[3][p].z, fmaf(xv.w,w[3][p].w, a3))));
            }
            #pragma unroll
            for (int d = 1; d < 16; d <<= 1) {
                a0 += __shfl_xor(a0, d, 64);
                a1 += __shfl_xor(a1, d, 64);
                a2 += __shfl_xor(a2, d, 64);
                a3 += __shfl_xor(a3, d, 64);
            }
            if (cc == 0) {
                const float PI = 3.14159265358979f;
                const int rloc = it*16 + wave*4 + rsub;
                float4 o;
                o.x = PI * tanh_fast(a0 + bv.x);
                o.y = PI * tanh_fast(a1 + bv.y);
                o.z = PI * tanh_fast(a2 + bv.z);
                o.w = PI * tanh_fast(a3 + bv.w);
                *(float4*)&fs[rloc][0] = o;
            }
            xv0 = nv0; xv1 = nv1; xv2 = nv2; xv3 = nv3;
        }
    }
    __syncthreads();

    // ---- phase 2: 4-qubit circuit, wave 0 only (64 rows, 1 row/lane)
    if (t < BROWS) {
        const float4 fv = ((const float4*)fs)[t];
        const float fq[4] = {fv.x, fv.y, fv.z, fv.w};
        const float IS2 = 0.70710678118654752f;
        float vr[4][2], vi[4][2];
        #pragma unroll
        for (int i = 0; i < 4; ++i) {
            const float fi = fq[i];
            const float f2 = fi*fi;
            const float ca = rsqrtf(1.0f + f2);
            const float ch = sqrtf(0.5f*(1.0f + ca));
            const float sh = copysignf(sqrtf(fmaxf(0.5f*(1.0f - ca), 0.0f)), fi);
            const float cb = rsqrtf(1.0f + f2*f2);
            const float cbh = sqrtf(0.5f*(1.0f + cb));
            const float sbh = sqrtf(fmaxf(0.5f*(1.0f - cb), 0.0f));
            const float u0 = (ch - sh) * IS2;
            const float u1 = (ch + sh) * IS2;
            vr[i][0] = u0 * cbh;  vi[i][0] = -u0 * sbh;
            vr[i][1] = u1 * cbh;  vi[i][1] =  u1 * sbh;
        }
        float ar[16], ai[16];
        #pragma unroll
        for (int i0 = 0; i0 < 2; ++i0)
        #pragma unroll
        for (int i1 = 0; i1 < 2; ++i1) {
            const float pr  = vr[0][i0]*vr[1][i1] - vi[0][i0]*vi[1][i1];
            const float pim = vr[0][i0]*vi[1][i1] + vi[0][i0]*vr[1][i1];
            #pragma unroll
            for (int i2 = 0; i2 < 2; ++i2)
            #pragma unroll
            for (int i3 = 0; i3 < 2; ++i3) {
                const float qr  = vr[2][i2]*vr[3][i3] - vi[2][i2]*vi[3][i3];
                const float qim = vr[2][i2]*vi[3][i3] + vi[2][i2]*vr[3][i3];
                const int idx = i0*8 + i1*4 + i2*2 + i3;
                ar[idx] = pr*qr - pim*qim;
                ai[idx] = pr*qim + pim*qr;
            }
        }
        #pragma unroll
        for (int l = 0; l < NLAYER; ++l) {
            constexpr int cpairs[8][2] = {{0,1},{1,2},{2,3},{3,0},{0,2},{1,3},{2,0},{3,1}};
            #pragma unroll
            for (int g = 0; g < 8; ++g) {
                const int bc = 8 >> cpairs[g][0];
                const int bt = 8 >> cpairs[g][1];
                #pragma unroll
                for (int m = 0; m < 16; ++m) {
                    if ((m & bc) && !(m & bt)) {    // register renames, zero insts
                        const int m2 = m | bt;
                        float tr = ar[m]; ar[m] = ar[m2]; ar[m2] = tr;
                        float ti = ai[m]; ai[m] = ai[m2]; ai[m2] = ti;
                    }
                }
            }
            #pragma unroll
            for (int i = 0; i < 4; ++i) {
                const float* u = &us[l*4 + i][0];
                const float u00r=u[0], u00i=u[1], u01r=u[2], u01i=u[3];
                const float u10r=u[4], u10i=u[5], u11r=u[6], u11i=u[7];
                const int bq = 8 >> i;
                #pragma unroll
                for (int m = 0; m < 16; ++m) {
                    if (!(m & bq)) {
                        const int m2 = m | bq;
                        const float a0r=ar[m], a0i=ai[m], a1r=ar[m2], a1i=ai[m2];
                        ar[m]  = u00r*a0r - u00i*a0i + u01r*a1r - u01i*a1i;
                        ai[m]  = u00r*a0i + u00i*a0r + u01r*a1i + u01i*a1r;
                        ar[m2] = u10r*a0r - u10i*a0i + u11r*a1r - u11i*a1i;
                        ai[m2] = u10r*a0i + u10i*a0r + u11r*a1i + u11i*a1r;
                    }
                }
            }
        }
        float z0=0.f, z1=0.f, z2=0.f, z3=0.f;
        #pragma unroll
        for (int m = 0; m < 16; ++m) {
            const float p = ar[m]*ar[m] + ai[m]*ai[m];
            z0 += (m & 8) ? -p : p;
            z1 += (m & 4) ? -p : p;
            z2 += (m & 2) ? -p : p;
            z3 += (m & 1) ? -p : p;
        }
        float4 qv; qv.x=z0; qv.y=z1; qv.z=z2; qv.w=z3;
        ((float4*)qs)[t] = qv;
    }
    __syncthreads();

    // ---- phase 3: out = q @ W2^T + b2 (each 16-lane group writes 1 KB rows)
    {
        const int j4 = t & 15;
        const int rb = t >> 4;           // 0..15
        float w2r[4][4], b2r[4];
        #pragma unroll
        for (int jj = 0; jj < 4; ++jj) {
            const int j = j4*4 + jj;
            #pragma unroll
            for (int i = 0; i < 4; ++i) w2r[jj][i] = w2s[j][i];
            b2r[jj] = b2s[j];
        }
        #pragma unroll
        for (int e = 0; e < 4; ++e) {
            const int r = rb*4 + e;
            const float4 q = ((const float4*)qs)[r];
            float4 o;
            o.x = fmaf(q.x,w2r[0][0], fmaf(q.y,w2r[0][1], fmaf(q.z,w2r[0][2], fmaf(q.w,w2r[0][3], b2r[0]))));
            o.y = fmaf(q.x,w2r[1][0], fmaf(q.y,w2r[1][1], fmaf(q.z,w2r[1][2], fmaf(q.w,w2r[1][3], b2r[1]))));
            o.z = fmaf(q.x,w2r[2][0], fmaf(q.y,w2r[2][1], fmaf(q.z,w2r[2][2], fmaf(q.w,w2r[2][3], b2r[2]))));
            o.w = fmaf(q.x,w2r[3][0], fmaf(q.y,w2r[3][1], fmaf(q.z,w2r[3][2], fmaf(q.w,w2r[3][3], b2r[3]))));
            ((float4*)(out + (size_t)(brow + r) * DOUT))[j4] = o;
        }
    }
}

extern "C" void kernel_launch(void* const* d_in, const int* in_sizes, int n_in,
                              void* d_out, int out_size, void* d_ws, size_t ws_size,
                              hipStream_t stream) {
    const float* x  = (const float*)d_in[0];
    const float* W1 = (const float*)d_in[1];
    const float* b1 = (const float*)d_in[2];
    const float* wt = (const float*)d_in[3];
    const float* W2 = (const float*)d_in[4];
    const float* b2 = (const float*)d_in[5];
    float* out = (float*)d_out;
    const int B = in_sizes[0] / DIN;        // 131072
    qp_fused<<<B / BROWS, TPB, 0, stream>>>(x, W1, b1, wt, W2, b2, out);
}

// Round 4
// 39.805 us; speedup vs baseline: 1.1987x; 1.0943x over previous
//
#include <hip/hip_runtime.h>
#include <math.h>

#define NQ 4
#define DIN 256
#define DOUT 64
#define NLAYER 2
#define TPB 256
#define BROWS 128           // rows per block; grid = B/128 = 1024 = 4 blocks/CU

__device__ __forceinline__ float tanh_fast(float y) {
    float e = __expf(2.0f * y);
    return 1.0f - 2.0f / (e + 1.0f);
}

__global__ __launch_bounds__(TPB, 4) void qp_fused(
    const float* __restrict__ x,  const float* __restrict__ W1,
    const float* __restrict__ b1, const float* __restrict__ wts,
    const float* __restrict__ W2, const float* __restrict__ b2,
    float* __restrict__ out)
{
    __shared__ __align__(16) float fs[BROWS][NQ];   // 2 KB
    __shared__ __align__(16) float qs[BROWS][NQ];   // 2 KB
    __shared__ __align__(16) float w2s[DOUT][NQ];   // 1 KB
    __shared__ __align__(16) float us[8][8];        // Rot gates
    __shared__ float b2s[DOUT];

    const int t = threadIdx.x;
    const int wave = t >> 6, lane = t & 63;
    const int half = lane >> 5;          // which of the wave's 2 rows
    const int cl   = lane & 31;          // float4 chunk index within row half
    const int brow = blockIdx.x * BROWS;

    // ---- phase 0: small staging (needed only after the phase-1 sync)
    if (t < 64) {
        ((float4*)&w2s[0][0])[t] = ((const float4*)W2)[t];
        b2s[t] = b2[t];
    }
    if (t < 8) {
        const float phi = wts[t*3 + 0], th = wts[t*3 + 1], om = wts[t*3 + 2];
        float sth, cth; sincosf(0.5f*th, &sth, &cth);
        float sp, cp;   sincosf(0.5f*(phi+om), &sp, &cp);
        float sm, cm;   sincosf(0.5f*(phi-om), &sm, &cm);
        us[t][0] =  cth*cp; us[t][1] = -cth*sp;
        us[t][2] = -sth*cm; us[t][3] = -sth*sm;
        us[t][4] =  sth*cm; us[t][5] = -sth*sm;
        us[t][6] =  cth*cp; us[t][7] =  cth*sp;
    }

    // ---- phase 1: f = pi*tanh(x@W1^T+b1); 32 lanes/row, W1 fragment = 32 VGPR
    {
        float4 w[4][2];
        #pragma unroll
        for (int q = 0; q < 4; ++q) {
            w[q][0] = ((const float4*)W1)[q*64 + cl];
            w[q][1] = ((const float4*)W1)[q*64 + 32 + cl];
        }
        const float4 bv = *(const float4*)b1;
        const int qsel = lane & 3;
        const float bsel = (qsel==0)?bv.x:(qsel==1)?bv.y:(qsel==2)?bv.z:bv.w;

        // wave handles rows it*8 + wave*2 + half, it = 0..15
        const int row0 = brow + wave*2 + half;
        const float4* xr = (const float4*)(x + (size_t)row0 * DIN);
        float4 xv0 = xr[cl], xv1 = xr[32 + cl];

        #pragma unroll
        for (int it = 0; it < BROWS/8; ++it) {
            float4 nv0, nv1;
            if (it < BROWS/8 - 1) {
                const float4* xn = (const float4*)(x + (size_t)(row0 + (it+1)*8) * DIN);
                nv0 = xn[cl]; nv1 = xn[32 + cl];
            }
            float a0, a1, a2, a3;
            a0 = fmaf(xv0.x,w[0][0].x, fmaf(xv0.y,w[0][0].y, fmaf(xv0.z,w[0][0].z, xv0.w*w[0][0].w)));
            a1 = fmaf(xv0.x,w[1][0].x, fmaf(xv0.y,w[1][0].y, fmaf(xv0.z,w[1][0].z, xv0.w*w[1][0].w)));
            a2 = fmaf(xv0.x,w[2][0].x, fmaf(xv0.y,w[2][0].y, fmaf(xv0.z,w[2][0].z, xv0.w*w[2][0].w)));
            a3 = fmaf(xv0.x,w[3][0].x, fmaf(xv0.y,w[3][0].y, fmaf(xv0.z,w[3][0].z, xv0.w*w[3][0].w)));
            a0 = fmaf(xv1.x,w[0][1].x, fmaf(xv1.y,w[0][1].y, fmaf(xv1.z,w[0][1].z, fmaf(xv1.w,w[0][1].w, a0))));
            a1 = fmaf(xv1.x,w[1][1].x, fmaf(xv1.y,w[1][1].y, fmaf(xv1.z,w[1][1].z, fmaf(xv1.w,w[1][1].w, a1))));
            a2 = fmaf(xv1.x,w[2][1].x, fmaf(xv1.y,w[2][1].y, fmaf(xv1.z,w[2][1].z, fmaf(xv1.w,w[2][1].w, a2))));
            a3 = fmaf(xv1.x,w[3][1].x, fmaf(xv1.y,w[3][1].y, fmaf(xv1.z,w[3][1].z, fmaf(xv1.w,w[3][1].w, a3))));

            // butterfly d=1,2 on all four accums
            a0 += __shfl_xor(a0, 1, 64);  a1 += __shfl_xor(a1, 1, 64);
            a2 += __shfl_xor(a2, 1, 64);  a3 += __shfl_xor(a3, 1, 64);
            a0 += __shfl_xor(a0, 2, 64);  a1 += __shfl_xor(a1, 2, 64);
            a2 += __shfl_xor(a2, 2, 64);  a3 += __shfl_xor(a3, 2, 64);
            // each lane keeps accumulator q = lane&3, then d=4,8,16
            float v = (qsel==0)?a0:(qsel==1)?a1:(qsel==2)?a2:a3;
            v += __shfl_xor(v, 4, 64);
            v += __shfl_xor(v, 8, 64);
            v += __shfl_xor(v, 16, 64);

            if (cl < 4) {
                const float PI = 3.14159265358979f;
                fs[it*8 + wave*2 + half][qsel] = PI * tanh_fast(v + bsel);
            }
            xv0 = nv0; xv1 = nv1;
        }
    }
    __syncthreads();

    // ---- phase 2: 4-qubit circuit, threads 0..127, one row each
    if (t < BROWS) {
        const float4 fv = ((const float4*)fs)[t];
        const float fq[4] = {fv.x, fv.y, fv.z, fv.w};
        const float IS2 = 0.70710678118654752f;
        float vr[4][2], vi[4][2];
        #pragma unroll
        for (int i = 0; i < 4; ++i) {
            const float fi = fq[i];
            const float f2 = fi*fi;
            const float ca = rsqrtf(1.0f + f2);
            const float ch = sqrtf(0.5f*(1.0f + ca));
            const float sh = copysignf(sqrtf(fmaxf(0.5f*(1.0f - ca), 0.0f)), fi);
            const float cb = rsqrtf(1.0f + f2*f2);
            const float cbh = sqrtf(0.5f*(1.0f + cb));
            const float sbh = sqrtf(fmaxf(0.5f*(1.0f - cb), 0.0f));
            const float u0 = (ch - sh) * IS2;
            const float u1 = (ch + sh) * IS2;
            vr[i][0] = u0 * cbh;  vi[i][0] = -u0 * sbh;
            vr[i][1] = u1 * cbh;  vi[i][1] =  u1 * sbh;
        }
        float ar[16], ai[16];
        #pragma unroll
        for (int i0 = 0; i0 < 2; ++i0)
        #pragma unroll
        for (int i1 = 0; i1 < 2; ++i1) {
            const float pr  = vr[0][i0]*vr[1][i1] - vi[0][i0]*vi[1][i1];
            const float pim = vr[0][i0]*vi[1][i1] + vi[0][i0]*vr[1][i1];
            #pragma unroll
            for (int i2 = 0; i2 < 2; ++i2)
            #pragma unroll
            for (int i3 = 0; i3 < 2; ++i3) {
                const float qr  = vr[2][i2]*vr[3][i3] - vi[2][i2]*vi[3][i3];
                const float qim = vr[2][i2]*vi[3][i3] + vi[2][i2]*vr[3][i3];
                const int idx = i0*8 + i1*4 + i2*2 + i3;
                ar[idx] = pr*qr - pim*qim;
                ai[idx] = pr*qim + pim*qr;
            }
        }
        #pragma unroll
        for (int l = 0; l < NLAYER; ++l) {
            constexpr int cpairs[8][2] = {{0,1},{1,2},{2,3},{3,0},{0,2},{1,3},{2,0},{3,1}};
            #pragma unroll
            for (int g = 0; g < 8; ++g) {
                const int bc = 8 >> cpairs[g][0];
                const int bt = 8 >> cpairs[g][1];
                #pragma unroll
                for (int m = 0; m < 16; ++m) {
                    if ((m & bc) && !(m & bt)) {
                        const int m2 = m | bt;
                        float tr = ar[m]; ar[m] = ar[m2]; ar[m2] = tr;
                        float ti = ai[m]; ai[m] = ai[m2]; ai[m2] = ti;
                    }
                }
            }
            #pragma unroll
            for (int i = 0; i < 4; ++i) {
                const float* u = &us[l*4 + i][0];
                const float u00r=u[0], u00i=u[1], u01r=u[2], u01i=u[3];
                const float u10r=u[4], u10i=u[5], u11r=u[6], u11i=u[7];
                const int bq = 8 >> i;
                #pragma unroll
                for (int m = 0; m < 16; ++m) {
                    if (!(m & bq)) {
                        const int m2 = m | bq;
                        const float a0r=ar[m], a0i=ai[m], a1r=ar[m2], a1i=ai[m2];
                        ar[m]  = u00r*a0r - u00i*a0i + u01r*a1r - u01i*a1i;
                        ai[m]  = u00r*a0i + u00i*a0r + u01r*a1i + u01i*a1r;
                        ar[m2] = u10r*a0r - u10i*a0i + u11r*a1r - u11i*a1i;
                        ai[m2] = u10r*a0i + u10i*a0r + u11r*a1i + u11i*a1r;
                    }
                }
            }
        }
        float z0=0.f, z1=0.f, z2=0.f, z3=0.f;
        #pragma unroll
        for (int m = 0; m < 16; ++m) {
            const float p = ar[m]*ar[m] + ai[m]*ai[m];
            z0 += (m & 8) ? -p : p;
            z1 += (m & 4) ? -p : p;
            z2 += (m & 2) ? -p : p;
            z3 += (m & 1) ? -p : p;
        }
        float4 qv; qv.x=z0; qv.y=z1; qv.z=z2; qv.w=z3;
        ((float4*)qs)[t] = qv;
    }
    __syncthreads();

    // ---- phase 3: out = q @ W2^T + b2, coalesced float4 stores
    {
        const int j4 = t & 15;
        const int rb = t >> 4;           // 0..15
        float w2r[4][4], b2r[4];
        #pragma unroll
        for (int jj = 0; jj < 4; ++jj) {
            const int j = j4*4 + jj;
            #pragma unroll
            for (int i = 0; i < 4; ++i) w2r[jj][i] = w2s[j][i];
            b2r[jj] = b2s[j];
        }
        #pragma unroll
        for (int e = 0; e < BROWS/16; ++e) {
            const int r = rb*(BROWS/16) + e;
            const float4 q = ((const float4*)qs)[r];
            float4 o;
            o.x = fmaf(q.x,w2r[0][0], fmaf(q.y,w2r[0][1], fmaf(q.z,w2r[0][2], fmaf(q.w,w2r[0][3], b2r[0]))));
            o.y = fmaf(q.x,w2r[1][0], fmaf(q.y,w2r[1][1], fmaf(q.z,w2r[1][2], fmaf(q.w,w2r[1][3], b2r[1]))));
            o.z = fmaf(q.x,w2r[2][0], fmaf(q.y,w2r[2][1], fmaf(q.z,w2r[2][2], fmaf(q.w,w2r[2][3], b2r[2]))));
            o.w = fmaf(q.x,w2r[3][0], fmaf(q.y,w2r[3][1], fmaf(q.z,w2r[3][2], fmaf(q.w,w2r[3][3], b2r[3]))));
            ((float4*)(out + (size_t)(brow + r) * DOUT))[j4] = o;
        }
    }
}

extern "C" void kernel_launch(void* const* d_in, const int* in_sizes, int n_in,
                              void* d_out, int out_size, void* d_ws, size_t ws_size,
                              hipStream_t stream) {
    const float* x  = (const float*)d_in[0];
    const float* W1 = (const float*)d_in[1];
    const float* b1 = (const float*)d_in[2];
    const float* wt = (const float*)d_in[3];
    const float* W2 = (const float*)d_in[4];
    const float* b2 = (const float*)d_in[5];
    float* out = (float*)d_out;
    const int B = in_sizes[0] / DIN;        // 131072
    qp_fused<<<B / BROWS, TPB, 0, stream>>>(x, W1, b1, wt, W2, b2, out);
}